// Round 7
// baseline (270.533 us; speedup 1.0000x reference)
//
#include <hip/hip_runtime.h>
#include <hip/hip_bf16.h>

#define NNODES 50000

typedef short bf16x8 __attribute__((ext_vector_type(8)));
typedef float f32x4 __attribute__((ext_vector_type(4)));

__device__ __forceinline__ unsigned short f2bf_rn(float f) {
    unsigned int u = __float_as_uint(f);
    return (unsigned short)((u + 0x7fffu + ((u >> 16) & 1u)) >> 16);
}

// ---------------- init: zero cnt + transpose both weights to bf16 ----------------

__global__ __launch_bounds__(256) void k_init(const float* __restrict__ W1,
                                              const float* __restrict__ W2,
                                              unsigned short* __restrict__ WT1,
                                              unsigned short* __restrict__ WT2,
                                              int* __restrict__ cnt, int N) {
    __shared__ float tile[128 * 129];  // +1 pad: conflict-free column reads
    int b = blockIdx.x;
    int t = threadIdx.x;
    if (b < 2) {
        const float* W = b ? W2 : W1;
        unsigned short* WT = b ? WT2 : WT1;
        for (int idx = t; idx < 128 * 128; idx += 256)
            tile[(idx >> 7) * 129 + (idx & 127)] = W[idx];
        __syncthreads();
        for (int idx = t; idx < 128 * 128; idx += 256) {
            int c = idx >> 7, k = idx & 127;
            WT[c * 128 + k] = f2bf_rn(tile[k * 129 + c]);
        }
    } else {
        int i = (b - 2) * 256 + t;
        if (i < N) cnt[i] = 0;
    }
}

// ---------------- degree count ----------------

__global__ __launch_bounds__(256) void k_count(const int* __restrict__ dst,
                                               int* __restrict__ cnt, int E) {
    int e = blockIdx.x * 256 + threadIdx.x;
    if (e < E) atomicAdd(&cnt[dst[e]], 1);
}

// per-block exclusive scan of cnt; block totals; fused dinv = rsqrt(cnt+1)
__global__ __launch_bounds__(256) void k_scan1(const int* __restrict__ cnt,
                                               int* __restrict__ offs,
                                               int* __restrict__ bsum,
                                               float* __restrict__ dinv, int N) {
    __shared__ int sh[256];
    int t = threadIdx.x;
    int i = blockIdx.x * 256 + t;
    int v = (i < N) ? cnt[i] : 0;
    if (i < N) dinv[i] = rsqrtf((float)v + 1.0f);  // +1 self-loop
    sh[t] = v;
    __syncthreads();
#pragma unroll
    for (int o = 1; o < 256; o <<= 1) {
        int u = (t >= o) ? sh[t - o] : 0;
        __syncthreads();
        sh[t] += u;
        __syncthreads();
    }
    if (i < N) offs[i] = sh[t] - v;
    if (t == 255) bsum[blockIdx.x] = sh[255];
}

// every block redundantly scans bsum (NB<=256) in LDS, then adds back + seeds cursor
__global__ __launch_bounds__(256) void k_scan3(int* __restrict__ offs,
                                               const int* __restrict__ bsum,
                                               int* __restrict__ cursor,
                                               int N, int E, int NB) {
    __shared__ int sh[256];
    __shared__ int orig[256];
    int t = threadIdx.x;
    int v = (t < NB) ? bsum[t] : 0;
    sh[t] = v;
    orig[t] = v;
    __syncthreads();
#pragma unroll
    for (int o = 1; o < 256; o <<= 1) {
        int u = (t >= o) ? sh[t - o] : 0;
        __syncthreads();
        sh[t] += u;
        __syncthreads();
    }
    int add = sh[blockIdx.x] - orig[blockIdx.x];  // exclusive prefix for this block
    int i = blockIdx.x * 256 + t;
    if (i < N) {
        int o = offs[i] + add;
        offs[i] = o;
        cursor[i] = o;
    }
    if (i == 0) offs[N] = E;
}

// CSR scatter: only src index (norms factored out of the sum)
__global__ __launch_bounds__(256) void k_scatter(const int* __restrict__ src,
                                                 const int* __restrict__ dst,
                                                 int* __restrict__ cursor,
                                                 int* __restrict__ csr_src, int E) {
    int e = blockIdx.x * 256 + threadIdx.x;
    if (e >= E) return;
    int s = src[e], d = dst[e];
    int pos = atomicAdd(&cursor[d], 1);
    csr_src[pos] = s;
}

// ---- dense MFMA GEMM, W register-resident, no LDS staging ----
// Per block: 64 nodes, 4 waves, 16 nodes/wave, full 128 cols per wave.
// A[m=lane&15][k=quad*8+j]; B[k=quad*8+j][n=lane&15]; C col=lane&15,row=quad*4+reg.

__device__ __forceinline__ bf16x8 load_a_frag(const float* p) {
    float4 v0 = *(const float4*)p;
    float4 v1 = *(const float4*)(p + 4);
    bf16x8 r;
    r[0] = (short)f2bf_rn(v0.x); r[1] = (short)f2bf_rn(v0.y);
    r[2] = (short)f2bf_rn(v0.z); r[3] = (short)f2bf_rn(v0.w);
    r[4] = (short)f2bf_rn(v1.x); r[5] = (short)f2bf_rn(v1.y);
    r[6] = (short)f2bf_rn(v1.z); r[7] = (short)f2bf_rn(v1.w);
    return r;
}
__device__ __forceinline__ bf16x8 load_a_frag(const unsigned short* p) {
    return *(const bf16x8*)p;  // already bf16, 16 B aligned
}

template <typename XT>
__global__ __launch_bounds__(256, 2) void k_gemm(const XT* __restrict__ X,
                                                 const unsigned short* __restrict__ WT,
                                                 unsigned short* __restrict__ Yb, int n) {
    __shared__ unsigned short Ep[4][16 * 136];  // per-wave epilogue pack tile (padded)
    int t = threadIdx.x, lane = t & 63, w = t >> 6;
    int m = lane & 15, quad = lane >> 4;
    int base = blockIdx.x * 64 + w * 16;
    int row = min(base + m, n - 1);  // duplicate-row trick: A row m only affects C row m

    // A fragments straight from global (HBM/L2), issued first
    bf16x8 a[4];
#pragma unroll
    for (int kt = 0; kt < 4; ++kt)
        a[kt] = load_a_frag(&X[(size_t)row * 128 + kt * 32 + quad * 8]);

    // Full W in registers: 32 frags = 128 VGPRs, loads are L2-hot
    bf16x8 bfr[4][8];
#pragma unroll
    for (int kt = 0; kt < 4; ++kt)
#pragma unroll
        for (int ct = 0; ct < 8; ++ct)
            bfr[kt][ct] = *(const bf16x8*)&WT[(ct * 16 + m) * 128 + kt * 32 + quad * 8];

    f32x4 acc[8];
#pragma unroll
    for (int i = 0; i < 8; ++i) acc[i] = f32x4{0.f, 0.f, 0.f, 0.f};
#pragma unroll
    for (int kt = 0; kt < 4; ++kt)
#pragma unroll
        for (int ct = 0; ct < 8; ++ct)
            acc[ct] = __builtin_amdgcn_mfma_f32_16x16x32_bf16(a[kt], bfr[kt][ct], acc[ct], 0, 0, 0);

    // packed epilogue: acc -> LDS (bf16) -> dwordx4 stores
    unsigned short* ep = Ep[w];
#pragma unroll
    for (int ct = 0; ct < 8; ++ct)
#pragma unroll
        for (int r = 0; r < 4; ++r)
            ep[(quad * 4 + r) * 136 + ct * 16 + m] = f2bf_rn(acc[ct][r]);
    __syncthreads();
    int rr = lane & 15, cc = lane >> 4;
    int orow = base + rr;
    if (orow < n) {
        const uint4* s = (const uint4*)&ep[rr * 136 + cc * 32];
        uint4* d = (uint4*)&Yb[(size_t)orow * 128 + cc * 32];
#pragma unroll
        for (int i = 0; i < 4; ++i) d[i] = s[i];
    }
}

// ---------------- sparse aggregation + bias + relu (bf16 gather) ----------------
// out_i = di * ( sum_j dinv[s_j]*x_{s_j} + di*x_i ) + b ; di = dinv[i]

__device__ __forceinline__ float bf_lo(unsigned int u) { return __uint_as_float(u << 16); }
__device__ __forceinline__ float bf_hi(unsigned int u) { return __uint_as_float(u & 0xffff0000u); }

__device__ __forceinline__ void store2(float* out, size_t idx, float ax, float ay) {
    ((float2*)out)[idx] = make_float2(ax, ay);
}
__device__ __forceinline__ void store2(unsigned short* out, size_t idx, float ax, float ay) {
    ((unsigned int*)out)[idx] = (unsigned)f2bf_rn(ax) | ((unsigned)f2bf_rn(ay) << 16);
}

template <typename OT>
__global__ __launch_bounds__(256) void k_aggregate(const unsigned int* __restrict__ xwb,
                                                   const int* __restrict__ offs,
                                                   const int* __restrict__ csr_src,
                                                   const float* __restrict__ dinv,
                                                   const float* __restrict__ bias,
                                                   OT* __restrict__ out, int n) {
    int lane = threadIdx.x & 63;
    int i = (blockIdx.x * 256 + threadIdx.x) >> 6;  // one wave per node
    if (i >= n) return;
    float di = dinv[i];
    unsigned int v0 = xwb[(size_t)i * 64 + lane];
    float ax = di * bf_lo(v0), ay = di * bf_hi(v0);  // self term di*x_i
    float px = 0.0f, py = 0.0f;
    int beg = offs[i], fin = offs[i + 1];
    int j = beg;
    for (; j + 8 <= fin; j += 8) {                   // 8 gathers in flight
        int s0 = csr_src[j],     s1 = csr_src[j + 1];
        int s2 = csr_src[j + 2], s3 = csr_src[j + 3];
        int s4 = csr_src[j + 4], s5 = csr_src[j + 5];
        int s6 = csr_src[j + 6], s7 = csr_src[j + 7];
        unsigned int u0 = xwb[(size_t)s0 * 64 + lane];
        unsigned int u1 = xwb[(size_t)s1 * 64 + lane];
        unsigned int u2 = xwb[(size_t)s2 * 64 + lane];
        unsigned int u3 = xwb[(size_t)s3 * 64 + lane];
        unsigned int u4 = xwb[(size_t)s4 * 64 + lane];
        unsigned int u5 = xwb[(size_t)s5 * 64 + lane];
        unsigned int u6 = xwb[(size_t)s6 * 64 + lane];
        unsigned int u7 = xwb[(size_t)s7 * 64 + lane];
        float w0 = dinv[s0], w1 = dinv[s1], w2 = dinv[s2], w3 = dinv[s3];
        float w4 = dinv[s4], w5 = dinv[s5], w6 = dinv[s6], w7 = dinv[s7];
        ax = fmaf(bf_lo(u0), w0, ax);  ay = fmaf(bf_hi(u0), w0, ay);
        px = fmaf(bf_lo(u1), w1, px);  py = fmaf(bf_hi(u1), w1, py);
        ax = fmaf(bf_lo(u2), w2, ax);  ay = fmaf(bf_hi(u2), w2, ay);
        px = fmaf(bf_lo(u3), w3, px);  py = fmaf(bf_hi(u3), w3, py);
        ax = fmaf(bf_lo(u4), w4, ax);  ay = fmaf(bf_hi(u4), w4, ay);
        px = fmaf(bf_lo(u5), w5, px);  py = fmaf(bf_hi(u5), w5, py);
        ax = fmaf(bf_lo(u6), w6, ax);  ay = fmaf(bf_hi(u6), w6, ay);
        px = fmaf(bf_lo(u7), w7, px);  py = fmaf(bf_hi(u7), w7, py);
    }
    for (; j < fin; ++j) {
        int s = csr_src[j];
        float wv = dinv[s];
        unsigned int u = xwb[(size_t)s * 64 + lane];
        ax = fmaf(bf_lo(u), wv, ax);
        ay = fmaf(bf_hi(u), wv, ay);
    }
    ax += px;
    ay += py;
    float bx = bias[lane * 2], by = bias[lane * 2 + 1];
    ax = fmaxf(fmaf(di, ax, bx), 0.0f);
    ay = fmaxf(fmaf(di, ay, by), 0.0f);
    store2(out, (size_t)i * 64 + lane, ax, ay);
}

// ---------------- launch ----------------

extern "C" void kernel_launch(void* const* d_in, const int* in_sizes, int n_in,
                              void* d_out, int out_size, void* d_ws, size_t ws_size,
                              hipStream_t stream) {
    const float* x  = (const float*)d_in[0];
    const int*   ei = (const int*)d_in[1];
    const float* W1 = (const float*)d_in[2];
    const float* b1 = (const float*)d_in[3];
    const float* W2 = (const float*)d_in[4];
    const float* b2 = (const float*)d_in[5];
    float* out = (float*)d_out;

    const int N = NNODES;
    const int E = in_sizes[1] / 2;  // 625000
    const int* src = ei;
    const int* dst = ei + E;
    const int NB = (N + 255) / 256;  // 196

    char* p = (char*)d_ws;
    size_t off = 0;
    auto take = [&](size_t bytes) -> void* {
        void* r = p + off;
        off = (off + bytes + 255) & ~(size_t)255;
        return r;
    };
    int*   cnt     = (int*)  take((size_t)N * 4);
    int*   offs    = (int*)  take((size_t)(N + 1) * 4);
    int*   cursor  = (int*)  take((size_t)N * 4);
    int*   bsum    = (int*)  take(256 * 4);
    float* dinv    = (float*)take((size_t)N * 4);
    int*   csr_src = (int*)  take((size_t)E * 4);
    unsigned short* w1t = (unsigned short*)take(128 * 128 * 2);
    unsigned short* w2t = (unsigned short*)take(128 * 128 * 2);
    unsigned short* xwb = (unsigned short*)take((size_t)N * 128 * 2);  // gemm out (bf16)
    unsigned short* hb  = (unsigned short*)take((size_t)N * 128 * 2);  // layer-1 act (bf16)

    // init: zero cnt + both weight transposes, one launch
    k_init<<<NB + 2, 256, 0, stream>>>(W1, W2, w1t, w2t, cnt, N);
    k_count<<<(E + 255) / 256, 256, 0, stream>>>(dst, cnt, E);
    k_scan1<<<NB, 256, 0, stream>>>(cnt, offs, bsum, dinv, N);
    k_scan3<<<NB, 256, 0, stream>>>(offs, bsum, cursor, N, E, NB);
    k_scatter<<<(E + 255) / 256, 256, 0, stream>>>(src, dst, cursor, csr_src, E);

    const int GB = (N + 63) / 64;  // 782 GEMM blocks

    // layer 1: hb = relu(Ahat @ (x@W1) + b1)   (bf16 activations)
    k_gemm<float><<<GB, 256, 0, stream>>>(x, w1t, xwb, N);
    k_aggregate<unsigned short><<<(N * 64 + 255) / 256, 256, 0, stream>>>(
        (const unsigned int*)xwb, offs, csr_src, dinv, b1, hb, N);

    // layer 2: out = relu(Ahat @ (hb@W2) + b2)
    k_gemm<unsigned short><<<GB, 256, 0, stream>>>(hb, w2t, xwb, N);
    k_aggregate<float><<<(N * 64 + 255) / 256, 256, 0, stream>>>(
        (const unsigned int*)xwb, offs, csr_src, dinv, b2, out, N);
}